// Round 7
// baseline (342.285 us; speedup 1.0000x reference)
//
#include <hip/hip_runtime.h>

typedef unsigned short u16;
typedef __attribute__((ext_vector_type(8))) short bf16x8;
typedef __attribute__((ext_vector_type(4))) short bf16x4;
typedef __attribute__((ext_vector_type(4))) float f32x4;

#define MFMA16(a, b, c) __builtin_amdgcn_mfma_f32_16x16x32_bf16(a, b, c, 0, 0, 0)

__device__ __forceinline__ u16 f2bf(float x) {
    unsigned u = __float_as_uint(x);
    return (u16)((u + 0x7fffu + ((u >> 16) & 1u)) >> 16);
}
__device__ __forceinline__ u16 f2bf_fast(float x) {  // round-half-up (P matrix only)
    return (u16)((__float_as_uint(x) + 0x8000u) >> 16);
}

// ---------------------------------------------------------------------------
// fp32 -> bf16 flat cast. n must be a multiple of 8*256.
// ---------------------------------------------------------------------------
__global__ __launch_bounds__(256) void castk(const float* __restrict__ src, u16* __restrict__ dst) {
    const int i = (blockIdx.x * 256 + threadIdx.x) * 8;
    float4 a = *(const float4*)(src + i);
    float4 b = *(const float4*)(src + i + 4);
    bf16x8 v;
    v[0] = (short)f2bf(a.x); v[1] = (short)f2bf(a.y);
    v[2] = (short)f2bf(a.z); v[3] = (short)f2bf(a.w);
    v[4] = (short)f2bf(b.x); v[5] = (short)f2bf(b.y);
    v[6] = (short)f2bf(b.z); v[7] = (short)f2bf(b.w);
    *(bf16x8*)(dst + i) = v;
}

// ---------------------------------------------------------------------------
// fp32 src[r][c] -> bf16 dst[c][r], 64x64 LDS tiles. grid R/64*C/64, block 256
// ---------------------------------------------------------------------------
__global__ __launch_bounds__(256) void tkern(const float* __restrict__ src, u16* __restrict__ dst,
                                             int R, int C) {
    const int tC = C >> 6;
    const int tr = (blockIdx.x / tC) << 6;
    const int tc = (blockIdx.x % tC) << 6;
    __shared__ u16 ls[64 * 68];
    const int tid = threadIdx.x;
#pragma unroll
    for (int rep = 0; rep < 2; ++rep) {
        const int f = tid * 8 + rep * 2048;
        const int r = f >> 6, c = f & 63;
        float4 a = *(const float4*)(src + (size_t)(tr + r) * C + tc + c);
        float4 b = *(const float4*)(src + (size_t)(tr + r) * C + tc + c + 4);
        bf16x4 lo, hi;
        lo[0] = (short)f2bf(a.x); lo[1] = (short)f2bf(a.y);
        lo[2] = (short)f2bf(a.z); lo[3] = (short)f2bf(a.w);
        hi[0] = (short)f2bf(b.x); hi[1] = (short)f2bf(b.y);
        hi[2] = (short)f2bf(b.z); hi[3] = (short)f2bf(b.w);
        *(bf16x4*)&ls[r * 68 + c] = lo;
        *(bf16x4*)&ls[r * 68 + c + 4] = hi;
    }
    __syncthreads();
#pragma unroll
    for (int rep = 0; rep < 2; ++rep) {
        const int f = tid * 8 + rep * 2048;
        const int rn = f >> 6, ck = f & 63;
        bf16x8 v;
#pragma unroll
        for (int j = 0; j < 8; ++j) v[j] = (short)ls[(ck + j) * 68 + rn];
        *(bf16x8*)(dst + (size_t)(tc + rn) * R + tr + ck) = v;
    }
}

// ---------------------------------------------------------------------------
// GEMM: C[m][n] = sum_k A[m][k] * Bt[n][k] + bias[n].  M=8192, K=1024, bf16.
// MODE 0: N=3072, scatter to Q(scaled)[BH][T][D], K[BH][T][D], V^T[BH][D][T].
// MODE 1: N=1024, fp32 store to Of[M][N].
// ---------------------------------------------------------------------------
template <int MODE>
__global__ __launch_bounds__(256) void gemm_k(const u16* __restrict__ A, const u16* __restrict__ Bt,
                                              const float* __restrict__ bias,
                                              u16* __restrict__ Qo, u16* __restrict__ Ko,
                                              u16* __restrict__ Vo, float* __restrict__ Of) {
    constexpr int Kd = 1024;
    const int tid = threadIdx.x;
    const int lane = tid & 63, wave = tid >> 6;
    const int wm = wave >> 1, wn = wave & 1;
    const int lr = lane & 15, lg = lane >> 4;
    const int mt = blockIdx.x & 63;
    const int nt = blockIdx.x >> 6;
    const int mbase = mt << 7, nbase = nt << 7;
    __shared__ u16 As[128 * 32];
    __shared__ u16 Bs[128 * 32];
    f32x4 acc[4][4];
#pragma unroll
    for (int i = 0; i < 4; ++i)
#pragma unroll
        for (int j = 0; j < 4; ++j) acc[i][j] = {0.f, 0.f, 0.f, 0.f};

    for (int kb = 0; kb < Kd; kb += 32) {
        __syncthreads();
#pragma unroll
        for (int rep = 0; rep < 2; ++rep) {
            const int f = tid * 8 + rep * 2048;
            const int r = f >> 5, c = f & 31;
            __builtin_amdgcn_global_load_lds(
                (const __attribute__((address_space(1))) void*)(A + (size_t)(mbase + r) * Kd + kb + c),
                (__attribute__((address_space(3))) void*)(As + f), 16, 0, 0);
            __builtin_amdgcn_global_load_lds(
                (const __attribute__((address_space(1))) void*)(Bt + (size_t)(nbase + r) * Kd + kb + c),
                (__attribute__((address_space(3))) void*)(Bs + f), 16, 0, 0);
        }
        __syncthreads();
        bf16x8 af[4], bfr[4];
#pragma unroll
        for (int i = 0; i < 4; ++i)
            af[i] = *(const bf16x8*)&As[(wm * 64 + i * 16 + lr) * 32 + lg * 8];
#pragma unroll
        for (int j = 0; j < 4; ++j)
            bfr[j] = *(const bf16x8*)&Bs[(wn * 64 + j * 16 + lr) * 32 + lg * 8];
#pragma unroll
        for (int i = 0; i < 4; ++i)
#pragma unroll
            for (int j = 0; j < 4; ++j) acc[i][j] = MFMA16(af[i], bfr[j], acc[i][j]);
    }

    const float QSCALE = 0.1803368801111137f;  // 0.125 * log2(e), folded into Q
#pragma unroll
    for (int j = 0; j < 4; ++j) {
        const int n = nbase + wn * 64 + j * 16 + lr;
        const float bj = bias[n];
        if (MODE == 0) {
            const int three = n >> 10;
            const int h = (n >> 6) & 15;
            const int d = n & 63;
#pragma unroll
            for (int i = 0; i < 4; ++i) {
#pragma unroll
                for (int r = 0; r < 4; ++r) {
                    const int m = mbase + wm * 64 + i * 16 + lg * 4 + r;
                    const int b = m >> 11, t = m & 2047;
                    const int bh = (b << 4) + h;
                    const float val = acc[i][j][r] + bj;
                    if (three == 0)
                        Qo[(((size_t)bh << 11) + t) * 64 + d] = f2bf(val * QSCALE);
                    else if (three == 1)
                        Ko[(((size_t)bh << 11) + t) * 64 + d] = f2bf(val);
                    else
                        Vo[(((size_t)bh << 6) + d) * 2048 + t] = f2bf(val);
                }
            }
        } else {
#pragma unroll
            for (int i = 0; i < 4; ++i) {
#pragma unroll
                for (int r = 0; r < 4; ++r) {
                    const int m = mbase + wm * 64 + i * 16 + lg * 4 + r;
                    Of[((size_t)m << 10) + n] = acc[i][j][r] + bj;
                }
            }
        }
    }
}

// ---------------------------------------------------------------------------
// Causal flash attention, LDS-staged K/V, double-buffered, MERGED subtiles.
// Q,K: [BH][T][D] bf16 (Q pre-scaled), Vt: [BH][D][T] bf16, Aout: [B][T][C].
// 1D grid 1024 with XCD swizzle (r6: FETCH 137->24.7 MB, keep). Block bx pairs
// q-tiles qb_hi=16+bx, qb_lo=15-bx; wave w owns 16 q rows of each.
// r7 changes (r6 was VALU+LDS-pipe bound: MfmaUtil 12.5, VALU 58.5, 32 b128
// K/V LDS reads per kt because each subtile re-read the same tiles):
//  (a) MERGED per-kt phases: one QK phase reads each K frag once and feeds
//      both subtiles' MFMAs; one PV phase reads each V frag once for both.
//      K/V LDS reads per kt: 32 -> 16 b128.
//  (b) EXACT defer-rescale: when __all(rmax <= m) the alpha path (exp2 +
//      4 LDS-shfl + 16 muls + m update) is skipped -- alpha would be 1.0
//      exactly, so this is bit-exact.
//  (c) rmax as fmaxf-triples (fuses to v_max3_f32), pairwise rsum tree.
// All state in named scalars/arrays with static indices (rule #20).
// NO 2nd launch_bounds arg (hard VGPR cap: r1/r3 catastrophic spills).
// ---------------------------------------------------------------------------
__global__ __launch_bounds__(256) void flash_attn(const u16* __restrict__ Q, const u16* __restrict__ Kg,
                                                  const u16* __restrict__ Vt, u16* __restrict__ Aout) {
    const int tid = threadIdx.x;
    const int lane = tid & 63, wave = tid >> 6;  // wave 0..3
    const int lr = lane & 15, lg = lane >> 4;
    const int bid = blockIdx.x;                  // 0..1023
    const int swz = (bid & 7) * 128 + (bid >> 3);
    const int bh = swz >> 4;     // 0..63
    const int bx = swz & 15;     // 0..15
    const int b = bh >> 4, h = bh & 15;
    const size_t base = (size_t)bh << 17;  // bh * 2048 * 64

    const int qb_hi = 16 + bx;
    const int qb_lo = 15 - bx;

    __shared__ u16 Ks[2][64 * 64];     // K tile  [kv_local][d], chunk-swizzled
    __shared__ u16 Vs[2][64 * 64];     // Vt tile [d][kv_local], chunk-swizzled
    __shared__ u16 Ps[4][16 * 64];     // per-wave P scratch, chunk-XOR-swizzled

    const int qbase0 = qb_hi * 64 + wave * 16;
    const int qbase1 = qb_lo * 64 + wave * 16;

    bf16x8 qf0[2], qf1[2];
    {
        const u16* p0 = Q + base + (size_t)(qbase0 + lr) * 64;
        qf0[0] = *(const bf16x8*)(p0 + lg * 8);
        qf0[1] = *(const bf16x8*)(p0 + 32 + lg * 8);
        const u16* p1 = Q + base + (size_t)(qbase1 + lr) * 64;
        qf1[0] = *(const bf16x8*)(p1 + lg * 8);
        qf1[1] = *(const bf16x8*)(p1 + 32 + lg * 8);
    }

    f32x4 o0[4], o1[4];
#pragma unroll
    for (int dt = 0; dt < 4; ++dt) {
        o0[dt] = {0.f, 0.f, 0.f, 0.f};
        o1[dt] = {0.f, 0.f, 0.f, 0.f};
    }
    float m0 = -INFINITY, l0 = 0.f, m1 = -INFINITY, l1 = 0.f;

    // staging geometry (kt-invariant): thread stages 16B chunks.
    // dest (linear): byte f = (tid + rep*256)*16 -> row = f>>7, chunk c =
    // (f>>4)&7.  source chunk cc = c ^ (row&7)  (rule 21 pre-swizzle).
    const int f0 = tid * 16;
    const int row0 = f0 >> 7, c0 = (f0 >> 4) & 7;
    const int cc0 = c0 ^ (row0 & 7);
    const int f1 = (tid + 256) * 16;
    const int row1 = f1 >> 7, c1 = (f1 >> 4) & 7;
    const int cc1 = c1 ^ (row1 & 7);

    const int xr = lr & 7;  // read-side XOR key

    auto stage = [&](int sel, int kt) {
        const size_t krow = base + (size_t)(kt * 64) * 64;
        __builtin_amdgcn_global_load_lds(
            (const __attribute__((address_space(1))) void*)(Kg + krow + (size_t)row0 * 64 + cc0 * 8),
            (__attribute__((address_space(3))) void*)(&Ks[sel][tid * 8]), 16, 0, 0);
        __builtin_amdgcn_global_load_lds(
            (const __attribute__((address_space(1))) void*)(Kg + krow + (size_t)row1 * 64 + cc1 * 8),
            (__attribute__((address_space(3))) void*)(&Ks[sel][2048 + tid * 8]), 16, 0, 0);
        __builtin_amdgcn_global_load_lds(
            (const __attribute__((address_space(1))) void*)(Vt + base + (size_t)row0 * 2048 + kt * 64 + cc0 * 8),
            (__attribute__((address_space(3))) void*)(&Vs[sel][tid * 8]), 16, 0, 0);
        __builtin_amdgcn_global_load_lds(
            (const __attribute__((address_space(1))) void*)(Vt + base + (size_t)row1 * 2048 + kt * 64 + cc1 * 8),
            (__attribute__((address_space(3))) void*)(&Vs[sel][2048 + tid * 8]), 16, 0, 0);
    };

    // softmax-finish for one subtile: in-place exp2 on s, update m/l/o,
    // produce A-layout P fragments via the Ps round trip.
    auto finish = [&](f32x4 (&s)[4], float& m, float& l, f32x4 (&o)[4],
                      bf16x8& pfa, bf16x8& pfb) {
        // rmax via max3-friendly triples (5 + 2 triples + 1)
        const float t0 = fmaxf(fmaxf(s[0][0], s[0][1]), s[0][2]);
        const float t1 = fmaxf(fmaxf(s[0][3], s[1][0]), s[1][1]);
        const float t2 = fmaxf(fmaxf(s[1][2], s[1][3]), s[2][0]);
        const float t3 = fmaxf(fmaxf(s[2][1], s[2][2]), s[2][3]);
        const float t4 = fmaxf(fmaxf(s[3][0], s[3][1]), s[3][2]);
        float rmax = fmaxf(fmaxf(fmaxf(t0, t1), t2), fmaxf(fmaxf(t3, t4), s[3][3]));
        rmax = fmaxf(rmax, __shfl_xor(rmax, 16));
        rmax = fmaxf(rmax, __shfl_xor(rmax, 32));

        float alpha = 1.f;
        if (!__all(rmax <= m)) {  // exact skip: if max didn't grow, alpha==1
            const float m_new = fmaxf(m, rmax);
            alpha = exp2f(m - m_new);
            float aq[4];
#pragma unroll
            for (int r = 0; r < 4; ++r) aq[r] = __shfl(alpha, (lane & 48) + lg * 4 + r);
#pragma unroll
            for (int dt = 0; dt < 4; ++dt)
#pragma unroll
                for (int r = 0; r < 4; ++r) o[dt][r] *= aq[r];
            m = m_new;
        }

#pragma unroll
        for (int rt = 0; rt < 4; ++rt)
#pragma unroll
            for (int r = 0; r < 4; ++r) s[rt][r] = exp2f(s[rt][r] - m);
        // pairwise rsum tree
        const float u0 = (s[0][0] + s[0][1]) + (s[0][2] + s[0][3]);
        const float u1 = (s[1][0] + s[1][1]) + (s[1][2] + s[1][3]);
        const float u2 = (s[2][0] + s[2][1]) + (s[2][2] + s[2][3]);
        const float u3 = (s[3][0] + s[3][1]) + (s[3][2] + s[3][3]);
        float rsum = (u0 + u1) + (u2 + u3);
        rsum += __shfl_xor(rsum, 16);
        rsum += __shfl_xor(rsum, 32);
        l = l * alpha + rsum;

        // P (C-layout) -> LDS (XOR-swizzled rows of 8x16B chunks) -> A-frags
        u16* psb = &Ps[wave][0];
#pragma unroll
        for (int rt = 0; rt < 4; ++rt) {
            bf16x4 pk;
#pragma unroll
            for (int r = 0; r < 4; ++r) pk[r] = (short)f2bf_fast(s[rt][r]);
            *(bf16x4*)&psb[lr * 64 + (((rt * 2 + (lg >> 1)) ^ xr) << 3) + ((lg & 1) << 2)] = pk;
        }
        pfa = *(const bf16x8*)&psb[lr * 64 + ((lg ^ xr) << 3)];
        pfb = *(const bf16x8*)&psb[lr * 64 + (((4 + lg) ^ xr) << 3)];
    };

    stage(0, 0);
    for (int kt = 0; kt <= qb_hi; ++kt) {
        const int cur = kt & 1;
        __syncthreads();  // vmcnt(0) drain precedes barrier -> buf[cur] ready;
                          // all waves done reading buf[cur^1]
        if (kt < qb_hi) stage(cur ^ 1, kt + 1);
        const bool do1 = (kt <= qb_lo);

        // ---- merged QK phase: each K frag read once, feeds both subtiles
        f32x4 s0[4], s1[4];
#pragma unroll
        for (int rt = 0; rt < 4; ++rt) {
            const int krow = rt * 16 + lr;
            const bf16x8 k0 = *(const bf16x8*)&Ks[cur][krow * 64 + ((lg) ^ xr) * 8];
            const bf16x8 k1 = *(const bf16x8*)&Ks[cur][krow * 64 + ((lg + 4) ^ xr) * 8];
            f32x4 z = {0.f, 0.f, 0.f, 0.f};
            z = MFMA16(k0, qf0[0], z);
            z = MFMA16(k1, qf0[1], z);
            s0[rt] = z;
            if (do1) {
                f32x4 w = {0.f, 0.f, 0.f, 0.f};
                w = MFMA16(k0, qf1[0], w);
                w = MFMA16(k1, qf1[1], w);
                s1[rt] = w;
            }
        }
        if (kt == qb_hi) {
            const int q_glob = qbase0 + lr;
#pragma unroll
            for (int rt = 0; rt < 4; ++rt)
#pragma unroll
                for (int r = 0; r < 4; ++r) {
                    const int kv = kt * 64 + rt * 16 + lg * 4 + r;
                    if (kv > q_glob) s0[rt][r] = -INFINITY;
                }
        }
        if (do1 && kt == qb_lo) {
            const int q_glob = qbase1 + lr;
#pragma unroll
            for (int rt = 0; rt < 4; ++rt)
#pragma unroll
                for (int r = 0; r < 4; ++r) {
                    const int kv = kt * 64 + rt * 16 + lg * 4 + r;
                    if (kv > q_glob) s1[rt][r] = -INFINITY;
                }
        }

        // ---- softmax finish (two independent chains; st1 reuses Ps after
        //      st0's reads -- in-order per-wave LDS makes this safe)
        bf16x8 pf00, pf01, pf10, pf11;
        finish(s0, m0, l0, o0, pf00, pf01);
        if (do1) finish(s1, m1, l1, o1, pf10, pf11);

        // ---- merged PV phase: each V frag read once, feeds both subtiles
#pragma unroll
        for (int dt = 0; dt < 4; ++dt) {
            const int vrow = dt * 16 + lr;
            const bf16x8 v0 = *(const bf16x8*)&Vs[cur][vrow * 64 + ((lg) ^ xr) * 8];
            const bf16x8 v1 = *(const bf16x8*)&Vs[cur][vrow * 64 + ((lg + 4) ^ xr) * 8];
            o0[dt] = MFMA16(pf00, v0, o0[dt]);
            o0[dt] = MFMA16(pf01, v1, o0[dt]);
            if (do1) {
                o1[dt] = MFMA16(pf10, v0, o1[dt]);
                o1[dt] = MFMA16(pf11, v1, o1[dt]);
            }
        }
    }

    {
        const float linv0 = 1.f / l0;
        float lq[4];
#pragma unroll
        for (int r = 0; r < 4; ++r) lq[r] = __shfl(linv0, (lane & 48) + lg * 4 + r);
#pragma unroll
        for (int dt = 0; dt < 4; ++dt)
#pragma unroll
            for (int r = 0; r < 4; ++r) {
                const int t = qbase0 + lg * 4 + r;
                Aout[(((size_t)(b << 11) + t) << 10) + h * 64 + dt * 16 + lr] =
                    f2bf(o0[dt][r] * lq[r]);
            }
        const float linv1 = 1.f / l1;
#pragma unroll
        for (int r = 0; r < 4; ++r) lq[r] = __shfl(linv1, (lane & 48) + lg * 4 + r);
#pragma unroll
        for (int dt = 0; dt < 4; ++dt)
#pragma unroll
            for (int r = 0; r < 4; ++r) {
                const int t = qbase1 + lg * 4 + r;
                Aout[(((size_t)(b << 11) + t) << 10) + h * 64 + dt * 16 + lr] =
                    f2bf(o1[dt][r] * lq[r]);
            }
    }
}

// ---------------------------------------------------------------------------
extern "C" void kernel_launch(void* const* d_in, const int* in_sizes, int n_in,
                              void* d_out, int out_size, void* d_ws, size_t ws_size,
                              hipStream_t stream) {
    (void)in_sizes; (void)n_in; (void)out_size; (void)ws_size;
    const float* x    = (const float*)d_in[0];
    const float* Wqkv = (const float*)d_in[2];
    const float* bqkv = (const float*)d_in[3];
    const float* Wout = (const float*)d_in[4];
    const float* bout = (const float*)d_in[5];
    float* out = (float*)d_out;

    char* ws = (char*)d_ws;
    u16* WqkvT = (u16*)(ws);                    //  6 MB: [3072][1024] bf16
    u16* WoutT = (u16*)(ws + 6291456);          //  2 MB: [1024][1024] bf16
    u16* xb    = (u16*)(ws + 8388608);          // 16 MB: [8192][1024] bf16
    u16* Qb    = (u16*)(ws + 25165824);         // 16 MB: [BH][T][D]
    u16* Kb    = (u16*)(ws + 41943040);         // 16 MB: [BH][T][D]
    u16* Vtb   = (u16*)(ws + 58720256);         // 16 MB: [BH][D][T]
    u16* Ab    = (u16*)(ws + 75497472);         // 16 MB: [B][T][C]

    castk<<<dim3(4096), 256, 0, stream>>>(x, xb);
    tkern<<<dim3(16 * 48), 256, 0, stream>>>(Wqkv, WqkvT, 1024, 3072);
    tkern<<<dim3(16 * 16), 256, 0, stream>>>(Wout, WoutT, 1024, 1024);
    gemm_k<0><<<dim3(64 * 24), 256, 0, stream>>>(xb, WqkvT, bqkv, Qb, Kb, Vtb, nullptr);
    flash_attn<<<dim3(1024), 256, 0, stream>>>(Qb, Kb, Vtb, Ab);
    gemm_k<1><<<dim3(64 * 8), 256, 0, stream>>>(Ab, WoutT, bout, nullptr, nullptr, nullptr, out);
}

// Round 8
// 321.125 us; speedup vs baseline: 1.0659x; 1.0659x over previous
//
#include <hip/hip_runtime.h>

typedef unsigned short u16;
typedef __attribute__((ext_vector_type(8))) short bf16x8;
typedef __attribute__((ext_vector_type(4))) short bf16x4;
typedef __attribute__((ext_vector_type(4))) float f32x4;

#define MFMA16(a, b, c) __builtin_amdgcn_mfma_f32_16x16x32_bf16(a, b, c, 0, 0, 0)

__device__ __forceinline__ u16 f2bf(float x) {
    unsigned u = __float_as_uint(x);
    return (u16)((u + 0x7fffu + ((u >> 16) & 1u)) >> 16);
}
__device__ __forceinline__ u16 f2bf_fast(float x) {  // round-half-up (P matrix only)
    return (u16)((__float_as_uint(x) + 0x8000u) >> 16);
}

// ---------------------------------------------------------------------------
// fp32 -> bf16 flat cast. n must be a multiple of 8*256.
// ---------------------------------------------------------------------------
__global__ __launch_bounds__(256) void castk(const float* __restrict__ src, u16* __restrict__ dst) {
    const int i = (blockIdx.x * 256 + threadIdx.x) * 8;
    float4 a = *(const float4*)(src + i);
    float4 b = *(const float4*)(src + i + 4);
    bf16x8 v;
    v[0] = (short)f2bf(a.x); v[1] = (short)f2bf(a.y);
    v[2] = (short)f2bf(a.z); v[3] = (short)f2bf(a.w);
    v[4] = (short)f2bf(b.x); v[5] = (short)f2bf(b.y);
    v[6] = (short)f2bf(b.z); v[7] = (short)f2bf(b.w);
    *(bf16x8*)(dst + i) = v;
}

// ---------------------------------------------------------------------------
// fp32 src[r][c] -> bf16 dst[c][r], 64x64 LDS tiles. grid R/64*C/64, block 256
// ---------------------------------------------------------------------------
__global__ __launch_bounds__(256) void tkern(const float* __restrict__ src, u16* __restrict__ dst,
                                             int R, int C) {
    const int tC = C >> 6;
    const int tr = (blockIdx.x / tC) << 6;
    const int tc = (blockIdx.x % tC) << 6;
    __shared__ u16 ls[64 * 68];
    const int tid = threadIdx.x;
#pragma unroll
    for (int rep = 0; rep < 2; ++rep) {
        const int f = tid * 8 + rep * 2048;
        const int r = f >> 6, c = f & 63;
        float4 a = *(const float4*)(src + (size_t)(tr + r) * C + tc + c);
        float4 b = *(const float4*)(src + (size_t)(tr + r) * C + tc + c + 4);
        bf16x4 lo, hi;
        lo[0] = (short)f2bf(a.x); lo[1] = (short)f2bf(a.y);
        lo[2] = (short)f2bf(a.z); lo[3] = (short)f2bf(a.w);
        hi[0] = (short)f2bf(b.x); hi[1] = (short)f2bf(b.y);
        hi[2] = (short)f2bf(b.z); hi[3] = (short)f2bf(b.w);
        *(bf16x4*)&ls[r * 68 + c] = lo;
        *(bf16x4*)&ls[r * 68 + c + 4] = hi;
    }
    __syncthreads();
#pragma unroll
    for (int rep = 0; rep < 2; ++rep) {
        const int f = tid * 8 + rep * 2048;
        const int rn = f >> 6, ck = f & 63;
        bf16x8 v;
#pragma unroll
        for (int j = 0; j < 8; ++j) v[j] = (short)ls[(ck + j) * 68 + rn];
        *(bf16x8*)(dst + (size_t)(tc + rn) * R + tr + ck) = v;
    }
}

// ---------------------------------------------------------------------------
// GEMM: C[m][n] = sum_k A[m][k] * Bt[n][k] + bias[n].  M=8192, K=1024, bf16.
// MODE 0: N=3072, scatter to Q(scaled)[BH][T][D], K[BH][T][D], V^T[BH][D][T].
// MODE 1: N=1024, fp32 store to Of[M][N].
// r8: XCD-aware block remap -- xcd = bid&7 owns a contiguous 8-mtile slice,
// so its A-slice (8x128x1024x2B = 2MB) is L2-resident (gemm<1>: B 2MB also).
// Aggregate operand re-read (~768MB L3 traffic for MODE 0) was the likely
// gemm bottleneck, not MFMA. Bijective: grids 1536/512 divisible by 8.
// ---------------------------------------------------------------------------
template <int MODE>
__global__ __launch_bounds__(256) void gemm_k(const u16* __restrict__ A, const u16* __restrict__ Bt,
                                              const float* __restrict__ bias,
                                              u16* __restrict__ Qo, u16* __restrict__ Ko,
                                              u16* __restrict__ Vo, float* __restrict__ Of) {
    constexpr int Kd = 1024;
    const int tid = threadIdx.x;
    const int lane = tid & 63, wave = tid >> 6;
    const int wm = wave >> 1, wn = wave & 1;
    const int lr = lane & 15, lg = lane >> 4;
    const int bid = blockIdx.x;
    const int xcd = bid & 7;
    const int cc = bid >> 3;
    const int mt = xcd * 8 + (cc & 7);   // contiguous 8-mtile slice per XCD
    const int nt = cc >> 3;
    const int mbase = mt << 7, nbase = nt << 7;
    __shared__ u16 As[128 * 32];
    __shared__ u16 Bs[128 * 32];
    f32x4 acc[4][4];
#pragma unroll
    for (int i = 0; i < 4; ++i)
#pragma unroll
        for (int j = 0; j < 4; ++j) acc[i][j] = {0.f, 0.f, 0.f, 0.f};

    for (int kb = 0; kb < Kd; kb += 32) {
        __syncthreads();
#pragma unroll
        for (int rep = 0; rep < 2; ++rep) {
            const int f = tid * 8 + rep * 2048;
            const int r = f >> 5, c = f & 31;
            __builtin_amdgcn_global_load_lds(
                (const __attribute__((address_space(1))) void*)(A + (size_t)(mbase + r) * Kd + kb + c),
                (__attribute__((address_space(3))) void*)(As + f), 16, 0, 0);
            __builtin_amdgcn_global_load_lds(
                (const __attribute__((address_space(1))) void*)(Bt + (size_t)(nbase + r) * Kd + kb + c),
                (__attribute__((address_space(3))) void*)(Bs + f), 16, 0, 0);
        }
        __syncthreads();
        bf16x8 af[4], bfr[4];
#pragma unroll
        for (int i = 0; i < 4; ++i)
            af[i] = *(const bf16x8*)&As[(wm * 64 + i * 16 + lr) * 32 + lg * 8];
#pragma unroll
        for (int j = 0; j < 4; ++j)
            bfr[j] = *(const bf16x8*)&Bs[(wn * 64 + j * 16 + lr) * 32 + lg * 8];
#pragma unroll
        for (int i = 0; i < 4; ++i)
#pragma unroll
            for (int j = 0; j < 4; ++j) acc[i][j] = MFMA16(af[i], bfr[j], acc[i][j]);
    }

    const float QSCALE = 0.1803368801111137f;  // 0.125 * log2(e), folded into Q
#pragma unroll
    for (int j = 0; j < 4; ++j) {
        const int n = nbase + wn * 64 + j * 16 + lr;
        const float bj = bias[n];
        if (MODE == 0) {
            const int three = n >> 10;
            const int h = (n >> 6) & 15;
            const int d = n & 63;
#pragma unroll
            for (int i = 0; i < 4; ++i) {
#pragma unroll
                for (int r = 0; r < 4; ++r) {
                    const int m = mbase + wm * 64 + i * 16 + lg * 4 + r;
                    const int b = m >> 11, t = m & 2047;
                    const int bh = (b << 4) + h;
                    const float val = acc[i][j][r] + bj;
                    if (three == 0)
                        Qo[(((size_t)bh << 11) + t) * 64 + d] = f2bf(val * QSCALE);
                    else if (three == 1)
                        Ko[(((size_t)bh << 11) + t) * 64 + d] = f2bf(val);
                    else
                        Vo[(((size_t)bh << 6) + d) * 2048 + t] = f2bf(val);
                }
            }
        } else {
#pragma unroll
            for (int i = 0; i < 4; ++i) {
#pragma unroll
                for (int r = 0; r < 4; ++r) {
                    const int m = mbase + wm * 64 + i * 16 + lg * 4 + r;
                    Of[((size_t)m << 10) + n] = acc[i][j][r] + bj;
                }
            }
        }
    }
}

// ---------------------------------------------------------------------------
// Causal flash attention, LDS-staged K/V, double-buffered (r6 structure,
// measured 115.4us -- r7's merged-subtile variant REGRESSED to 132us by
// idling the MFMA pipe through the merged softmax; sequential per-subtile
// process() restored). r8 grafts only the local, structure-free wins:
//  (b) EXACT defer-rescale: when __all(rmax <= m) the alpha path (exp2 +
//      4 LDS-shfl + 16 muls + l-scale) is skipped -- alpha would be exactly
//      1.0. Skip probability ~ kt/(kt+1) on random scores.
//  (c) rmax via fmaxf-triples (fuses to v_max3_f32), pairwise rsum tree.
// Everything else verbatim r6: XCD grid swizzle (FETCH 137->24.7MB), K/V
// chunk-XOR swizzle via pre-swizzled global source (rule 21), Ps XOR-swizzle,
// one barrier per kt with stage(kt+1) issued before compute(kt).
// NO 2nd launch_bounds arg (hard VGPR cap: r1 (256,4)->64, r3 (128,2)->128,
// both catastrophic spills).
// ---------------------------------------------------------------------------
__global__ __launch_bounds__(256) void flash_attn(const u16* __restrict__ Q, const u16* __restrict__ Kg,
                                                  const u16* __restrict__ Vt, u16* __restrict__ Aout) {
    const int tid = threadIdx.x;
    const int lane = tid & 63, wave = tid >> 6;  // wave 0..3
    const int lr = lane & 15, lg = lane >> 4;
    const int bid = blockIdx.x;                  // 0..1023
    const int swz = (bid & 7) * 128 + (bid >> 3);
    const int bh = swz >> 4;     // 0..63
    const int bx = swz & 15;     // 0..15
    const int b = bh >> 4, h = bh & 15;
    const size_t base = (size_t)bh << 17;  // bh * 2048 * 64

    const int qb_hi = 16 + bx;
    const int qb_lo = 15 - bx;

    __shared__ u16 Ks[2][64 * 64];     // K tile  [kv_local][d], chunk-swizzled
    __shared__ u16 Vs[2][64 * 64];     // Vt tile [d][kv_local], chunk-swizzled
    __shared__ u16 Ps[4][16 * 64];     // per-wave P scratch, chunk-XOR-swizzled

    // subtile q-bases: 0 = hi slice, 1 = lo slice (16 rows each)
    int qbase[2];
    qbase[0] = qb_hi * 64 + wave * 16;
    qbase[1] = qb_lo * 64 + wave * 16;

    bf16x8 qf[2][2];
#pragma unroll
    for (int st = 0; st < 2; ++st) {
        const u16* p = Q + base + (size_t)(qbase[st] + lr) * 64;
        qf[st][0] = *(const bf16x8*)(p + lg * 8);
        qf[st][1] = *(const bf16x8*)(p + 32 + lg * 8);
    }

    f32x4 o[2][4];
#pragma unroll
    for (int st = 0; st < 2; ++st)
#pragma unroll
        for (int dt = 0; dt < 4; ++dt) o[st][dt] = {0.f, 0.f, 0.f, 0.f};
    float m_[2] = {-INFINITY, -INFINITY};
    float l_[2] = {0.f, 0.f};

    // staging geometry (kt-invariant): thread stages 16B chunks.
    // dest (linear): byte f = (tid + rep*256)*16 -> row = f>>7, chunk c =
    // (f>>4)&7.  source chunk cc = c ^ (row&7)  (rule 21 pre-swizzle).
    const int f0 = tid * 16;
    const int row0 = f0 >> 7, c0 = (f0 >> 4) & 7;
    const int cc0 = c0 ^ (row0 & 7);
    const int f1 = (tid + 256) * 16;
    const int row1 = f1 >> 7, c1 = (f1 >> 4) & 7;
    const int cc1 = c1 ^ (row1 & 7);

    const int xr = lr & 7;  // read-side XOR key

    auto stage = [&](int sel, int kt) {
        const size_t krow = base + (size_t)(kt * 64) * 64;
        __builtin_amdgcn_global_load_lds(
            (const __attribute__((address_space(1))) void*)(Kg + krow + (size_t)row0 * 64 + cc0 * 8),
            (__attribute__((address_space(3))) void*)(&Ks[sel][tid * 8]), 16, 0, 0);
        __builtin_amdgcn_global_load_lds(
            (const __attribute__((address_space(1))) void*)(Kg + krow + (size_t)row1 * 64 + cc1 * 8),
            (__attribute__((address_space(3))) void*)(&Ks[sel][2048 + tid * 8]), 16, 0, 0);
        __builtin_amdgcn_global_load_lds(
            (const __attribute__((address_space(1))) void*)(Vt + base + (size_t)row0 * 2048 + kt * 64 + cc0 * 8),
            (__attribute__((address_space(3))) void*)(&Vs[sel][tid * 8]), 16, 0, 0);
        __builtin_amdgcn_global_load_lds(
            (const __attribute__((address_space(1))) void*)(Vt + base + (size_t)row1 * 2048 + kt * 64 + cc1 * 8),
            (__attribute__((address_space(3))) void*)(&Vs[sel][2048 + tid * 8]), 16, 0, 0);
    };

    auto process = [&](int sel, int st, bool diag, int kt) {
        // S^T[kv][q] = K * Q^T  (kv = kt*64 + rt*16 + lg*4 + reg, q = lr)
        f32x4 s[4];
#pragma unroll
        for (int rt = 0; rt < 4; ++rt) {
            const int krow = rt * 16 + lr;
            const bf16x8 k0 = *(const bf16x8*)&Ks[sel][krow * 64 + ((lg) ^ xr) * 8];
            const bf16x8 k1 = *(const bf16x8*)&Ks[sel][krow * 64 + ((lg + 4) ^ xr) * 8];
            f32x4 z = {0.f, 0.f, 0.f, 0.f};
            z = MFMA16(k0, qf[st][0], z);
            z = MFMA16(k1, qf[st][1], z);
            s[rt] = z;
        }
        if (diag) {
            const int q_glob = qbase[st] + lr;
#pragma unroll
            for (int rt = 0; rt < 4; ++rt)
#pragma unroll
                for (int r = 0; r < 4; ++r) {
                    const int kv = kt * 64 + rt * 16 + lg * 4 + r;
                    if (kv > q_glob) s[rt][r] = -INFINITY;
                }
        }
        // rmax via max3-friendly triples
        const float t0 = fmaxf(fmaxf(s[0][0], s[0][1]), s[0][2]);
        const float t1 = fmaxf(fmaxf(s[0][3], s[1][0]), s[1][1]);
        const float t2 = fmaxf(fmaxf(s[1][2], s[1][3]), s[2][0]);
        const float t3 = fmaxf(fmaxf(s[2][1], s[2][2]), s[2][3]);
        const float t4 = fmaxf(fmaxf(s[3][0], s[3][1]), s[3][2]);
        float rmax = fmaxf(fmaxf(fmaxf(t0, t1), t2), fmaxf(fmaxf(t3, t4), s[3][3]));
        rmax = fmaxf(rmax, __shfl_xor(rmax, 16));
        rmax = fmaxf(rmax, __shfl_xor(rmax, 32));

        if (!__all(rmax <= m_[st])) {  // exact skip: max didn't grow -> alpha==1
            const float m_new = fmaxf(m_[st], rmax);
            const float alpha = exp2f(m_[st] - m_new);
            float aq[4];
#pragma unroll
            for (int r = 0; r < 4; ++r) aq[r] = __shfl(alpha, (lane & 48) + lg * 4 + r);
#pragma unroll
            for (int dt = 0; dt < 4; ++dt)
#pragma unroll
                for (int r = 0; r < 4; ++r) o[st][dt][r] *= aq[r];
            l_[st] *= alpha;
            m_[st] = m_new;
        }

#pragma unroll
        for (int rt = 0; rt < 4; ++rt)
#pragma unroll
            for (int r = 0; r < 4; ++r) s[rt][r] = exp2f(s[rt][r] - m_[st]);
        // pairwise rsum tree
        const float u0 = (s[0][0] + s[0][1]) + (s[0][2] + s[0][3]);
        const float u1 = (s[1][0] + s[1][1]) + (s[1][2] + s[1][3]);
        const float u2 = (s[2][0] + s[2][1]) + (s[2][2] + s[2][3]);
        const float u3 = (s[3][0] + s[3][1]) + (s[3][2] + s[3][3]);
        float rsum = (u0 + u1) + (u2 + u3);
        rsum += __shfl_xor(rsum, 16);
        rsum += __shfl_xor(rsum, 32);
        l_[st] += rsum;

        // P (C-layout) -> LDS (XOR-swizzled rows of 8x16B chunks) -> A-frags
        u16* psb = &Ps[wave][0];
#pragma unroll
        for (int rt = 0; rt < 4; ++rt) {
            bf16x4 pk;
#pragma unroll
            for (int r = 0; r < 4; ++r) pk[r] = (short)f2bf_fast(s[rt][r]);
            *(bf16x4*)&psb[lr * 64 + (((rt * 2 + (lg >> 1)) ^ xr) << 3) + ((lg & 1) << 2)] = pk;
        }

        const bf16x8 pf0 = *(const bf16x8*)&psb[lr * 64 + ((lg ^ xr) << 3)];
        const bf16x8 pf1 = *(const bf16x8*)&psb[lr * 64 + (((4 + lg) ^ xr) << 3)];
#pragma unroll
        for (int dt = 0; dt < 4; ++dt) {
            const int vrow = dt * 16 + lr;
            const bf16x8 v0 = *(const bf16x8*)&Vs[sel][vrow * 64 + ((lg) ^ xr) * 8];
            const bf16x8 v1 = *(const bf16x8*)&Vs[sel][vrow * 64 + ((lg + 4) ^ xr) * 8];
            o[st][dt] = MFMA16(pf0, v0, o[st][dt]);
            o[st][dt] = MFMA16(pf1, v1, o[st][dt]);
        }
    };

    stage(0, 0);
    for (int kt = 0; kt <= qb_hi; ++kt) {
        const int cur = kt & 1;
        __syncthreads();  // vmcnt(0) drain precedes barrier -> buf[cur] ready;
                          // all waves done reading buf[cur^1]
        if (kt < qb_hi) stage(cur ^ 1, kt + 1);
        process(cur, 0, kt == qb_hi, kt);
        if (kt <= qb_lo) process(cur, 1, kt == qb_lo, kt);
    }

#pragma unroll
    for (int st = 0; st < 2; ++st) {
        const float linv = 1.f / l_[st];
        float lq[4];
#pragma unroll
        for (int r = 0; r < 4; ++r) lq[r] = __shfl(linv, (lane & 48) + lg * 4 + r);
#pragma unroll
        for (int dt = 0; dt < 4; ++dt)
#pragma unroll
            for (int r = 0; r < 4; ++r) {
                const int t = qbase[st] + lg * 4 + r;
                Aout[(((size_t)(b << 11) + t) << 10) + h * 64 + dt * 16 + lr] =
                    f2bf(o[st][dt][r] * lq[r]);
            }
    }
}

// ---------------------------------------------------------------------------
extern "C" void kernel_launch(void* const* d_in, const int* in_sizes, int n_in,
                              void* d_out, int out_size, void* d_ws, size_t ws_size,
                              hipStream_t stream) {
    (void)in_sizes; (void)n_in; (void)out_size; (void)ws_size;
    const float* x    = (const float*)d_in[0];
    const float* Wqkv = (const float*)d_in[2];
    const float* bqkv = (const float*)d_in[3];
    const float* Wout = (const float*)d_in[4];
    const float* bout = (const float*)d_in[5];
    float* out = (float*)d_out;

    char* ws = (char*)d_ws;
    u16* WqkvT = (u16*)(ws);                    //  6 MB: [3072][1024] bf16
    u16* WoutT = (u16*)(ws + 6291456);          //  2 MB: [1024][1024] bf16
    u16* xb    = (u16*)(ws + 8388608);          // 16 MB: [8192][1024] bf16
    u16* Qb    = (u16*)(ws + 25165824);         // 16 MB: [BH][T][D]
    u16* Kb    = (u16*)(ws + 41943040);         // 16 MB: [BH][T][D]
    u16* Vtb   = (u16*)(ws + 58720256);         // 16 MB: [BH][D][T]
    u16* Ab    = (u16*)(ws + 75497472);         // 16 MB: [B][T][C]

    castk<<<dim3(4096), 256, 0, stream>>>(x, xb);
    tkern<<<dim3(16 * 48), 256, 0, stream>>>(Wqkv, WqkvT, 1024, 3072);
    tkern<<<dim3(16 * 16), 256, 0, stream>>>(Wout, WoutT, 1024, 1024);
    gemm_k<0><<<dim3(64 * 24), 256, 0, stream>>>(xb, WqkvT, bqkv, Qb, Kb, Vtb, nullptr);
    flash_attn<<<dim3(1024), 256, 0, stream>>>(Qb, Kb, Vtb, Ab);
    gemm_k<1><<<dim3(64 * 8), 256, 0, stream>>>(Ab, WoutT, bout, nullptr, nullptr, nullptr, out);
}

// Round 9
// 317.051 us; speedup vs baseline: 1.0796x; 1.0128x over previous
//
#include <hip/hip_runtime.h>

typedef unsigned short u16;
typedef __attribute__((ext_vector_type(8))) short bf16x8;
typedef __attribute__((ext_vector_type(4))) short bf16x4;
typedef __attribute__((ext_vector_type(4))) float f32x4;

#define MFMA16(a, b, c) __builtin_amdgcn_mfma_f32_16x16x32_bf16(a, b, c, 0, 0, 0)

__device__ __forceinline__ u16 f2bf(float x) {
    unsigned u = __float_as_uint(x);
    return (u16)((u + 0x7fffu + ((u >> 16) & 1u)) >> 16);
}
__device__ __forceinline__ u16 f2bf_fast(float x) {  // round-half-up (P matrix only)
    return (u16)((__float_as_uint(x) + 0x8000u) >> 16);
}

// ---------------------------------------------------------------------------
// fp32 -> bf16 flat cast. n must be a multiple of 8*256.
// ---------------------------------------------------------------------------
__global__ __launch_bounds__(256) void castk(const float* __restrict__ src, u16* __restrict__ dst) {
    const int i = (blockIdx.x * 256 + threadIdx.x) * 8;
    float4 a = *(const float4*)(src + i);
    float4 b = *(const float4*)(src + i + 4);
    bf16x8 v;
    v[0] = (short)f2bf(a.x); v[1] = (short)f2bf(a.y);
    v[2] = (short)f2bf(a.z); v[3] = (short)f2bf(a.w);
    v[4] = (short)f2bf(b.x); v[5] = (short)f2bf(b.y);
    v[6] = (short)f2bf(b.z); v[7] = (short)f2bf(b.w);
    *(bf16x8*)(dst + i) = v;
}

// ---------------------------------------------------------------------------
// fp32 src[r][c] -> bf16 dst[c][r], 64x64 LDS tiles. grid R/64*C/64, block 256
// ---------------------------------------------------------------------------
__global__ __launch_bounds__(256) void tkern(const float* __restrict__ src, u16* __restrict__ dst,
                                             int R, int C) {
    const int tC = C >> 6;
    const int tr = (blockIdx.x / tC) << 6;
    const int tc = (blockIdx.x % tC) << 6;
    __shared__ u16 ls[64 * 68];
    const int tid = threadIdx.x;
#pragma unroll
    for (int rep = 0; rep < 2; ++rep) {
        const int f = tid * 8 + rep * 2048;
        const int r = f >> 6, c = f & 63;
        float4 a = *(const float4*)(src + (size_t)(tr + r) * C + tc + c);
        float4 b = *(const float4*)(src + (size_t)(tr + r) * C + tc + c + 4);
        bf16x4 lo, hi;
        lo[0] = (short)f2bf(a.x); lo[1] = (short)f2bf(a.y);
        lo[2] = (short)f2bf(a.z); lo[3] = (short)f2bf(a.w);
        hi[0] = (short)f2bf(b.x); hi[1] = (short)f2bf(b.y);
        hi[2] = (short)f2bf(b.z); hi[3] = (short)f2bf(b.w);
        *(bf16x4*)&ls[r * 68 + c] = lo;
        *(bf16x4*)&ls[r * 68 + c + 4] = hi;
    }
    __syncthreads();
#pragma unroll
    for (int rep = 0; rep < 2; ++rep) {
        const int f = tid * 8 + rep * 2048;
        const int rn = f >> 6, ck = f & 63;
        bf16x8 v;
#pragma unroll
        for (int j = 0; j < 8; ++j) v[j] = (short)ls[(ck + j) * 68 + rn];
        *(bf16x8*)(dst + (size_t)(tc + rn) * R + tr + ck) = v;
    }
}

// ---------------------------------------------------------------------------
// GEMM: C[m][n] = sum_k A[m][k] * Bt[n][k] + bias[n].  M=8192, K=1024, bf16.
// MODE 0: N=3072, scatter to Q(scaled)[BH][T][D], K[BH][T][D], V^T[BH][D][T].
// MODE 1: N=1024, fp32 store to Of[M][N].
// r9: T3-minimum schedule (r6-flash-validated): LDS double-buffer As/Bs[2],
// per K-step { barrier -> stage(buf^1, kb+32) -> compute(buf) }. The r8 loop
// had TWO barriers per K-step with the stage round-trip fully exposed (zero
// compute between gload_lds issue and the vmcnt(0) drain) x32 steps -- the
// m233 stall class, est. ~460 TF. Now the drain at the next barrier waits on
// loads issued a full compute phase (16 MFMA + 8 ds_read) earlier.
// Hazards (as r6): RAW -- issuing wave drains own vmcnt(0) at the barrier
// before any wave reads; WAR -- stage(buf^1) issued after the barrier that
// closes the previous iteration's reads of buf^1.
// XCD-aware remap kept from r8 (neutral but harmless; better L2 with dbuf).
// ---------------------------------------------------------------------------
template <int MODE>
__global__ __launch_bounds__(256) void gemm_k(const u16* __restrict__ A, const u16* __restrict__ Bt,
                                              const float* __restrict__ bias,
                                              u16* __restrict__ Qo, u16* __restrict__ Ko,
                                              u16* __restrict__ Vo, float* __restrict__ Of) {
    constexpr int Kd = 1024;
    const int tid = threadIdx.x;
    const int lane = tid & 63, wave = tid >> 6;
    const int wm = wave >> 1, wn = wave & 1;
    const int lr = lane & 15, lg = lane >> 4;
    const int bid = blockIdx.x;
    const int xcd = bid & 7;
    const int cc = bid >> 3;
    const int mt = xcd * 8 + (cc & 7);   // contiguous 8-mtile slice per XCD
    const int nt = cc >> 3;
    const int mbase = mt << 7, nbase = nt << 7;
    __shared__ u16 As[2][128 * 32];
    __shared__ u16 Bs[2][128 * 32];
    f32x4 acc[4][4];
#pragma unroll
    for (int i = 0; i < 4; ++i)
#pragma unroll
        for (int j = 0; j < 4; ++j) acc[i][j] = {0.f, 0.f, 0.f, 0.f};

    // staging: thread stages 2x16B per tile (A and B), kt-invariant dest.
    auto stage = [&](int sel, int kb) {
#pragma unroll
        for (int rep = 0; rep < 2; ++rep) {
            const int f = tid * 8 + rep * 2048;
            const int r = f >> 5, c = f & 31;
            __builtin_amdgcn_global_load_lds(
                (const __attribute__((address_space(1))) void*)(A + (size_t)(mbase + r) * Kd + kb + c),
                (__attribute__((address_space(3))) void*)(&As[sel][f]), 16, 0, 0);
            __builtin_amdgcn_global_load_lds(
                (const __attribute__((address_space(1))) void*)(Bt + (size_t)(nbase + r) * Kd + kb + c),
                (__attribute__((address_space(3))) void*)(&Bs[sel][f]), 16, 0, 0);
        }
    };

    stage(0, 0);
    for (int kb = 0; kb < Kd; kb += 32) {
        const int cur = (kb >> 5) & 1;
        __syncthreads();  // vmcnt(0) drain precedes barrier -> buf[cur] ready;
                          // all waves done reading buf[cur^1]
        if (kb + 32 < Kd) stage(cur ^ 1, kb + 32);
        bf16x8 af[4], bfr[4];
#pragma unroll
        for (int i = 0; i < 4; ++i)
            af[i] = *(const bf16x8*)&As[cur][(wm * 64 + i * 16 + lr) * 32 + lg * 8];
#pragma unroll
        for (int j = 0; j < 4; ++j)
            bfr[j] = *(const bf16x8*)&Bs[cur][(wn * 64 + j * 16 + lr) * 32 + lg * 8];
#pragma unroll
        for (int i = 0; i < 4; ++i)
#pragma unroll
            for (int j = 0; j < 4; ++j) acc[i][j] = MFMA16(af[i], bfr[j], acc[i][j]);
    }

    const float QSCALE = 0.1803368801111137f;  // 0.125 * log2(e), folded into Q
#pragma unroll
    for (int j = 0; j < 4; ++j) {
        const int n = nbase + wn * 64 + j * 16 + lr;
        const float bj = bias[n];
        if (MODE == 0) {
            const int three = n >> 10;
            const int h = (n >> 6) & 15;
            const int d = n & 63;
#pragma unroll
            for (int i = 0; i < 4; ++i) {
#pragma unroll
                for (int r = 0; r < 4; ++r) {
                    const int m = mbase + wm * 64 + i * 16 + lg * 4 + r;
                    const int b = m >> 11, t = m & 2047;
                    const int bh = (b << 4) + h;
                    const float val = acc[i][j][r] + bj;
                    if (three == 0)
                        Qo[(((size_t)bh << 11) + t) * 64 + d] = f2bf(val * QSCALE);
                    else if (three == 1)
                        Ko[(((size_t)bh << 11) + t) * 64 + d] = f2bf(val);
                    else
                        Vo[(((size_t)bh << 6) + d) * 2048 + t] = f2bf(val);
                }
            }
        } else {
#pragma unroll
            for (int i = 0; i < 4; ++i) {
#pragma unroll
                for (int r = 0; r < 4; ++r) {
                    const int m = mbase + wm * 64 + i * 16 + lg * 4 + r;
                    Of[((size_t)m << 10) + n] = acc[i][j][r] + bj;
                }
            }
        }
    }
}

// ---------------------------------------------------------------------------
// Causal flash attention, LDS-staged K/V, double-buffered (r6 structure +
// r8 local grafts: exact defer-rescale, max3-triple rmax, pairwise rsum).
// Measured 114.5us (r8). UNCHANGED this round (control).
// NO 2nd launch_bounds arg (hard VGPR cap: r1 (256,4)->64, r3 (128,2)->128,
// both catastrophic spills).
// ---------------------------------------------------------------------------
__global__ __launch_bounds__(256) void flash_attn(const u16* __restrict__ Q, const u16* __restrict__ Kg,
                                                  const u16* __restrict__ Vt, u16* __restrict__ Aout) {
    const int tid = threadIdx.x;
    const int lane = tid & 63, wave = tid >> 6;  // wave 0..3
    const int lr = lane & 15, lg = lane >> 4;
    const int bid = blockIdx.x;                  // 0..1023
    const int swz = (bid & 7) * 128 + (bid >> 3);
    const int bh = swz >> 4;     // 0..63
    const int bx = swz & 15;     // 0..15
    const int b = bh >> 4, h = bh & 15;
    const size_t base = (size_t)bh << 17;  // bh * 2048 * 64

    const int qb_hi = 16 + bx;
    const int qb_lo = 15 - bx;

    __shared__ u16 Ks[2][64 * 64];     // K tile  [kv_local][d], chunk-swizzled
    __shared__ u16 Vs[2][64 * 64];     // Vt tile [d][kv_local], chunk-swizzled
    __shared__ u16 Ps[4][16 * 64];     // per-wave P scratch, chunk-XOR-swizzled

    // subtile q-bases: 0 = hi slice, 1 = lo slice (16 rows each)
    int qbase[2];
    qbase[0] = qb_hi * 64 + wave * 16;
    qbase[1] = qb_lo * 64 + wave * 16;

    bf16x8 qf[2][2];
#pragma unroll
    for (int st = 0; st < 2; ++st) {
        const u16* p = Q + base + (size_t)(qbase[st] + lr) * 64;
        qf[st][0] = *(const bf16x8*)(p + lg * 8);
        qf[st][1] = *(const bf16x8*)(p + 32 + lg * 8);
    }

    f32x4 o[2][4];
#pragma unroll
    for (int st = 0; st < 2; ++st)
#pragma unroll
        for (int dt = 0; dt < 4; ++dt) o[st][dt] = {0.f, 0.f, 0.f, 0.f};
    float m_[2] = {-INFINITY, -INFINITY};
    float l_[2] = {0.f, 0.f};

    // staging geometry (kt-invariant): thread stages 16B chunks.
    // dest (linear): byte f = (tid + rep*256)*16 -> row = f>>7, chunk c =
    // (f>>4)&7.  source chunk cc = c ^ (row&7)  (rule 21 pre-swizzle).
    const int f0 = tid * 16;
    const int row0 = f0 >> 7, c0 = (f0 >> 4) & 7;
    const int cc0 = c0 ^ (row0 & 7);
    const int f1 = (tid + 256) * 16;
    const int row1 = f1 >> 7, c1 = (f1 >> 4) & 7;
    const int cc1 = c1 ^ (row1 & 7);

    const int xr = lr & 7;  // read-side XOR key

    auto stage = [&](int sel, int kt) {
        const size_t krow = base + (size_t)(kt * 64) * 64;
        __builtin_amdgcn_global_load_lds(
            (const __attribute__((address_space(1))) void*)(Kg + krow + (size_t)row0 * 64 + cc0 * 8),
            (__attribute__((address_space(3))) void*)(&Ks[sel][tid * 8]), 16, 0, 0);
        __builtin_amdgcn_global_load_lds(
            (const __attribute__((address_space(1))) void*)(Kg + krow + (size_t)row1 * 64 + cc1 * 8),
            (__attribute__((address_space(3))) void*)(&Ks[sel][2048 + tid * 8]), 16, 0, 0);
        __builtin_amdgcn_global_load_lds(
            (const __attribute__((address_space(1))) void*)(Vt + base + (size_t)row0 * 2048 + kt * 64 + cc0 * 8),
            (__attribute__((address_space(3))) void*)(&Vs[sel][tid * 8]), 16, 0, 0);
        __builtin_amdgcn_global_load_lds(
            (const __attribute__((address_space(1))) void*)(Vt + base + (size_t)row1 * 2048 + kt * 64 + cc1 * 8),
            (__attribute__((address_space(3))) void*)(&Vs[sel][2048 + tid * 8]), 16, 0, 0);
    };

    auto process = [&](int sel, int st, bool diag, int kt) {
        // S^T[kv][q] = K * Q^T  (kv = kt*64 + rt*16 + lg*4 + reg, q = lr)
        f32x4 s[4];
#pragma unroll
        for (int rt = 0; rt < 4; ++rt) {
            const int krow = rt * 16 + lr;
            const bf16x8 k0 = *(const bf16x8*)&Ks[sel][krow * 64 + ((lg) ^ xr) * 8];
            const bf16x8 k1 = *(const bf16x8*)&Ks[sel][krow * 64 + ((lg + 4) ^ xr) * 8];
            f32x4 z = {0.f, 0.f, 0.f, 0.f};
            z = MFMA16(k0, qf[st][0], z);
            z = MFMA16(k1, qf[st][1], z);
            s[rt] = z;
        }
        if (diag) {
            const int q_glob = qbase[st] + lr;
#pragma unroll
            for (int rt = 0; rt < 4; ++rt)
#pragma unroll
                for (int r = 0; r < 4; ++r) {
                    const int kv = kt * 64 + rt * 16 + lg * 4 + r;
                    if (kv > q_glob) s[rt][r] = -INFINITY;
                }
        }
        // rmax via max3-friendly triples
        const float t0 = fmaxf(fmaxf(s[0][0], s[0][1]), s[0][2]);
        const float t1 = fmaxf(fmaxf(s[0][3], s[1][0]), s[1][1]);
        const float t2 = fmaxf(fmaxf(s[1][2], s[1][3]), s[2][0]);
        const float t3 = fmaxf(fmaxf(s[2][1], s[2][2]), s[2][3]);
        const float t4 = fmaxf(fmaxf(s[3][0], s[3][1]), s[3][2]);
        float rmax = fmaxf(fmaxf(fmaxf(t0, t1), t2), fmaxf(fmaxf(t3, t4), s[3][3]));
        rmax = fmaxf(rmax, __shfl_xor(rmax, 16));
        rmax = fmaxf(rmax, __shfl_xor(rmax, 32));

        if (!__all(rmax <= m_[st])) {  // exact skip: max didn't grow -> alpha==1
            const float m_new = fmaxf(m_[st], rmax);
            const float alpha = exp2f(m_[st] - m_new);
            float aq[4];
#pragma unroll
            for (int r = 0; r < 4; ++r) aq[r] = __shfl(alpha, (lane & 48) + lg * 4 + r);
#pragma unroll
            for (int dt = 0; dt < 4; ++dt)
#pragma unroll
                for (int r = 0; r < 4; ++r) o[st][dt][r] *= aq[r];
            l_[st] *= alpha;
            m_[st] = m_new;
        }

#pragma unroll
        for (int rt = 0; rt < 4; ++rt)
#pragma unroll
            for (int r = 0; r < 4; ++r) s[rt][r] = exp2f(s[rt][r] - m_[st]);
        // pairwise rsum tree
        const float u0 = (s[0][0] + s[0][1]) + (s[0][2] + s[0][3]);
        const float u1 = (s[1][0] + s[1][1]) + (s[1][2] + s[1][3]);
        const float u2 = (s[2][0] + s[2][1]) + (s[2][2] + s[2][3]);
        const float u3 = (s[3][0] + s[3][1]) + (s[3][2] + s[3][3]);
        float rsum = (u0 + u1) + (u2 + u3);
        rsum += __shfl_xor(rsum, 16);
        rsum += __shfl_xor(rsum, 32);
        l_[st] += rsum;

        // P (C-layout) -> LDS (XOR-swizzled rows of 8x16B chunks) -> A-frags
        u16* psb = &Ps[wave][0];
#pragma unroll
        for (int rt = 0; rt < 4; ++rt) {
            bf16x4 pk;
#pragma unroll
            for (int r = 0; r < 4; ++r) pk[r] = (short)f2bf_fast(s[rt][r]);
            *(bf16x4*)&psb[lr * 64 + (((rt * 2 + (lg >> 1)) ^ xr) << 3) + ((lg & 1) << 2)] = pk;
        }

        const bf16x8 pf0 = *(const bf16x8*)&psb[lr * 64 + ((lg ^ xr) << 3)];
        const bf16x8 pf1 = *(const bf16x8*)&psb[lr * 64 + (((4 + lg) ^ xr) << 3)];
#pragma unroll
        for (int dt = 0; dt < 4; ++dt) {
            const int vrow = dt * 16 + lr;
            const bf16x8 v0 = *(const bf16x8*)&Vs[sel][vrow * 64 + ((lg) ^ xr) * 8];
            const bf16x8 v1 = *(const bf16x8*)&Vs[sel][vrow * 64 + ((lg + 4) ^ xr) * 8];
            o[st][dt] = MFMA16(pf0, v0, o[st][dt]);
            o[st][dt] = MFMA16(pf1, v1, o[st][dt]);
        }
    };

    stage(0, 0);
    for (int kt = 0; kt <= qb_hi; ++kt) {
        const int cur = kt & 1;
        __syncthreads();  // vmcnt(0) drain precedes barrier -> buf[cur] ready;
                          // all waves done reading buf[cur^1]
        if (kt < qb_hi) stage(cur ^ 1, kt + 1);
        process(cur, 0, kt == qb_hi, kt);
        if (kt <= qb_lo) process(cur, 1, kt == qb_lo, kt);
    }

#pragma unroll
    for (int st = 0; st < 2; ++st) {
        const float linv = 1.f / l_[st];
        float lq[4];
#pragma unroll
        for (int r = 0; r < 4; ++r) lq[r] = __shfl(linv, (lane & 48) + lg * 4 + r);
#pragma unroll
        for (int dt = 0; dt < 4; ++dt)
#pragma unroll
            for (int r = 0; r < 4; ++r) {
                const int t = qbase[st] + lg * 4 + r;
                Aout[(((size_t)(b << 11) + t) << 10) + h * 64 + dt * 16 + lr] =
                    f2bf(o[st][dt][r] * lq[r]);
            }
    }
}

// ---------------------------------------------------------------------------
extern "C" void kernel_launch(void* const* d_in, const int* in_sizes, int n_in,
                              void* d_out, int out_size, void* d_ws, size_t ws_size,
                              hipStream_t stream) {
    (void)in_sizes; (void)n_in; (void)out_size; (void)ws_size;
    const float* x    = (const float*)d_in[0];
    const float* Wqkv = (const float*)d_in[2];
    const float* bqkv = (const float*)d_in[3];
    const float* Wout = (const float*)d_in[4];
    const float* bout = (const float*)d_in[5];
    float* out = (float*)d_out;

    char* ws = (char*)d_ws;
    u16* WqkvT = (u16*)(ws);                    //  6 MB: [3072][1024] bf16
    u16* WoutT = (u16*)(ws + 6291456);          //  2 MB: [1024][1024] bf16
    u16* xb    = (u16*)(ws + 8388608);          // 16 MB: [8192][1024] bf16
    u16* Qb    = (u16*)(ws + 25165824);         // 16 MB: [BH][T][D]
    u16* Kb    = (u16*)(ws + 41943040);         // 16 MB: [BH][T][D]
    u16* Vtb   = (u16*)(ws + 58720256);         // 16 MB: [BH][D][T]
    u16* Ab    = (u16*)(ws + 75497472);         // 16 MB: [B][T][C]

    castk<<<dim3(4096), 256, 0, stream>>>(x, xb);
    tkern<<<dim3(16 * 48), 256, 0, stream>>>(Wqkv, WqkvT, 1024, 3072);
    tkern<<<dim3(16 * 16), 256, 0, stream>>>(Wout, WoutT, 1024, 1024);
    gemm_k<0><<<dim3(64 * 24), 256, 0, stream>>>(xb, WqkvT, bqkv, Qb, Kb, Vtb, nullptr);
    flash_attn<<<dim3(1024), 256, 0, stream>>>(Qb, Kb, Vtb, Ab);
    gemm_k<1><<<dim3(64 * 8), 256, 0, stream>>>(Ab, WoutT, bout, nullptr, nullptr, nullptr, out);
}